// Round 12
// baseline (517.179 us; speedup 1.0000x reference)
//
#include <hip/hip_runtime.h>
#include <hip/hip_bf16.h>
#include <math.h>

// ---------------- constants (problem shapes) ----------------
#define B_    2
#define SSRC_ 4093
#define D_    768
#define H_    12
#define DH_   64
#define FF_   3072
#define NG_   3
#define W_    256
#define S_    4096
#define NC_   16
#define NSPLIT_ 16
#define QB_   128

typedef __attribute__((ext_vector_type(8))) short frag_ab;   // 8 bf16 (4 VGPRs)
typedef __attribute__((ext_vector_type(4))) float f32x4;     // 4 fp32 acc

// async global->LDS, 16B per lane (linear dest: base + lane*16)
#define GL16(gp, lp) __builtin_amdgcn_global_load_lds( \
    (const __attribute__((address_space(1))) void*)(gp), \
    (__attribute__((address_space(3))) void*)(lp), 16, 0, 0)

// ---------------- helpers ----------------
__device__ __forceinline__ float bflo(unsigned int w) {
    union { float f; unsigned int i; } c; c.i = w << 16; return c.f;
}
__device__ __forceinline__ float bfhi(unsigned int w) {
    union { float f; unsigned int i; } c; c.i = w & 0xffff0000u; return c.f;
}
__device__ __forceinline__ void unp8(uint4 t, float* o) {
    o[0] = bflo(t.x); o[1] = bfhi(t.x); o[2] = bflo(t.y); o[3] = bfhi(t.y);
    o[4] = bflo(t.z); o[5] = bfhi(t.z); o[6] = bflo(t.w); o[7] = bfhi(t.w);
}
__device__ __forceinline__ unsigned short f2bfu(float x) {
    __hip_bfloat16 h = __float2bfloat16(x);
    return *reinterpret_cast<unsigned short*>(&h);
}

__device__ __forceinline__ float block_sum(float v, float* red) {
    int tid = threadIdx.x;
    red[tid] = v;
    __syncthreads();
#pragma unroll
    for (int off = 128; off >= 1; off >>= 1) {
        if (tid < off) red[tid] += red[tid + off];
        __syncthreads();
    }
    float r = red[0];
    __syncthreads();
    return r;
}

__device__ __forceinline__ float block_max(float v, float* red) {
    int tid = threadIdx.x;
    red[tid] = v;
    __syncthreads();
#pragma unroll
    for (int off = 128; off >= 1; off >>= 1) {
        if (tid < off) red[tid] = fmaxf(red[tid], red[tid + off]);
        __syncthreads();
    }
    float r = red[0];
    __syncthreads();
    return r;
}

__device__ __forceinline__ void storeO(float* p, float v) { *p = v; }
__device__ __forceinline__ void storeO(__hip_bfloat16* p, float v) { *p = __float2bfloat16(v); }

// ---------------- embedding + LN (writes f32 X and bf16 Xb) ----------------
__global__ __launch_bounds__(256) void embed_ln_k(
    const int* __restrict__ src, const float* __restrict__ we,
    const float* __restrict__ pe, const float* __restrict__ gam,
    const float* __restrict__ bet, float* __restrict__ X,
    __hip_bfloat16* __restrict__ Xb) {
    __shared__ float red[256];
    int row = blockIdx.x;
    int b = row >> 12;
    int s = row & (S_ - 1);
    int tid = threadIdx.x;
    int id = (s < NG_) ? (50261 + s) : src[b * SSRC_ + (s - NG_)];
    const float* wr = we + (size_t)id * D_;
    const float* pr = pe + (size_t)s * D_;
    float v[3];
    float lsum = 0.f;
#pragma unroll
    for (int j = 0; j < 3; ++j) {
        int c = tid + j * 256;
        v[j] = wr[c] + pr[c];
        lsum += v[j];
    }
    float mu = block_sum(lsum, red) * (1.0f / 768.0f);
    float ls2 = 0.f;
#pragma unroll
    for (int j = 0; j < 3; ++j) { float d = v[j] - mu; ls2 += d * d; }
    float var = block_sum(ls2, red) * (1.0f / 768.0f);
    float rs = rsqrtf(var + 1e-5f);
    float* xr = X + (size_t)row * D_;
    __hip_bfloat16* xbr = Xb + (size_t)row * D_;
#pragma unroll
    for (int j = 0; j < 3; ++j) {
        int c = tid + j * 256;
        float o = (v[j] - mu) * rs * gam[c] + bet[c];
        xr[c] = o;
        xbr[c] = __float2bfloat16(o);
    }
}

// ---------------- residual + LN : out = LN(x + y [+ y2]), optional bf16 mirror ----------------
__global__ __launch_bounds__(256) void residual_ln_k(
    const float* __restrict__ x, const float* __restrict__ y,
    const float* __restrict__ y2, const float* __restrict__ gam,
    const float* __restrict__ bet, float* __restrict__ out,
    __hip_bfloat16* __restrict__ outb) {
    __shared__ float red[256];
    int row = blockIdx.x;
    int tid = threadIdx.x;
    const float* xr = x + (size_t)row * D_;
    const float* yr = y + (size_t)row * D_;
    const float* y2r = y2 ? y2 + (size_t)row * D_ : nullptr;
    float v[3];
    float lsum = 0.f;
#pragma unroll
    for (int j = 0; j < 3; ++j) {
        int c = tid + j * 256;
        v[j] = xr[c] + yr[c];
        if (y2r) v[j] += y2r[c];
        lsum += v[j];
    }
    float mu = block_sum(lsum, red) * (1.0f / 768.0f);
    float ls2 = 0.f;
#pragma unroll
    for (int j = 0; j < 3; ++j) { float d = v[j] - mu; ls2 += d * d; }
    float var = block_sum(ls2, red) * (1.0f / 768.0f);
    float rs = rsqrtf(var + 1e-5f);
    float* orow = out + (size_t)row * D_;
    __hip_bfloat16* obr = outb ? outb + (size_t)row * D_ : nullptr;
#pragma unroll
    for (int j = 0; j < 3; ++j) {
        int c = tid + j * 256;
        float o = (v[j] - mu) * rs * gam[c] + bet[c];
        orow[c] = o;
        if (obr) obr[c] = __float2bfloat16(o);
    }
}

// ---------------- transpose-convert: nmat x (W[K,N] f32 -> WT[N,K] bf16) ----------------
__global__ __launch_bounds__(256) void convt_k(
    const float* __restrict__ W, __hip_bfloat16* __restrict__ WT,
    int K, int N, int npb /* = N/32 */) {
    __shared__ float tile[32][33];
    int mat = blockIdx.x / npb;
    int bx = blockIdx.x - mat * npb;
    int by = blockIdx.y;
    const float* Wm = W + (size_t)mat * K * N;
    __hip_bfloat16* WTm = WT + (size_t)mat * N * K;
    int tx = threadIdx.x & 31, ty = threadIdx.x >> 5;
#pragma unroll
    for (int i = 0; i < 32; i += 8)
        tile[ty + i][tx] = Wm[(size_t)(by * 32 + ty + i) * N + bx * 32 + tx];
    __syncthreads();
#pragma unroll
    for (int i = 0; i < 32; i += 8)
        WTm[(size_t)(bx * 32 + ty + i) * K + by * 32 + tx] = __float2bfloat16(tile[tx][ty + i]);
}

// ---------------- pack layer-0 mega bias: [ab0,ab1,ab2,ab4,ab5] -> 3840 ----------------
__global__ void pack_bias_k(const float* __restrict__ ab, float* __restrict__ dst) {
    int j = blockIdx.x * 256 + threadIdx.x;
    if (j >= 5 * 768) return;
    int mat = j / 768, c = j - mat * 768;
    int i = (mat < 3) ? mat : mat + 1;
    dst[j] = ab[i * 768 + c];
}

// ---------------- MFMA GEMM (global_load_lds staged, m97 structure) ----------------
// C[M,N] = A[M,K]bf16 @ BT[N,K]^T + bias
// LDS k-slot XOR-swizzle (slot ^= row&3): pre-swizzled GLOBAL source + swizzled READ
// (rule #21: global_load_lds dest must stay linear). Cuts phase-local 4-way
// ds_read_b128 bank conflict to 2-way (free).
// EPI: 0 = f32 out, 1 = bf16 out, 2 = bf16 gelu(out)
// SPLIT: 1 => output col c -> matrix c/768 (stride matstride bf16 elems)
// gridDim.z > 1 => split-K: z-th K-slice, f32 partial at Cout + z*M*N (EPI must be 0);
//                 bias added only in z==0 slice.
template <int EPI, int SPLIT>
__global__ __launch_bounds__(256) void mfma_gemm_k(
    const __hip_bfloat16* __restrict__ A, const __hip_bfloat16* __restrict__ BT,
    const float* __restrict__ bias, void* __restrict__ Cout,
    int M, int N, int K, size_t matstride) {
    __shared__ __align__(16) __hip_bfloat16 As[4096];
    __shared__ __align__(16) __hip_bfloat16 Bs[4096];
    int tid = threadIdx.x;
    int lane = tid & 63;
    int w = tid >> 6, wr = w >> 1, wc = w & 1;
    int brow = blockIdx.y * 128, bcol = blockIdx.x * 128;
    int z = blockIdx.z, nz = gridDim.z;
    int Kz = K / nz;
    int r0 = tid >> 2;
    int k0 = (((tid & 3) ^ (r0 & 3)) * 8);   // pre-swizzled global k-chunk for this lane's slot
    const __hip_bfloat16* Ag0 = A + (size_t)(brow + r0) * K + z * Kz + k0;
    const __hip_bfloat16* Ag1 = Ag0 + (size_t)64 * K;
    const __hip_bfloat16* Bg0 = BT + (size_t)(bcol + r0) * K + z * Kz + k0;
    const __hip_bfloat16* Bg1 = Bg0 + (size_t)64 * K;
    __hip_bfloat16* lA0 = &As[tid * 8];
    __hip_bfloat16* lA1 = &As[tid * 8 + 2048];
    __hip_bfloat16* lB0 = &Bs[tid * 8];
    __hip_bfloat16* lB1 = &Bs[tid * 8 + 2048];

    f32x4 acc[4][4];
#pragma unroll
    for (int m = 0; m < 4; ++m)
#pragma unroll
        for (int n = 0; n < 4; ++n) acc[m][n] = (f32x4){0.f, 0.f, 0.f, 0.f};

    int l15 = lane & 15, kb = lane >> 4;
    int xkb = kb ^ (l15 & 3);                // swizzled read slot (row&3 == l15&3 for all frags)
    int aoff = (wr * 64 + l15) * 32 + xkb * 8;
    int boff = (wc * 64 + l15) * 32 + xkb * 8;

    for (int kt = 0; kt < Kz; kt += 32) {
        GL16(Ag0 + kt, lA0);
        GL16(Ag1 + kt, lA1);
        GL16(Bg0 + kt, lB0);
        GL16(Bg1 + kt, lB1);
        __syncthreads();
        frag_ab af[4], bf[4];
#pragma unroll
        for (int m = 0; m < 4; ++m) af[m] = *(const frag_ab*)&As[aoff + m * 512];
#pragma unroll
        for (int n = 0; n < 4; ++n) bf[n] = *(const frag_ab*)&Bs[boff + n * 512];
        __builtin_amdgcn_s_setprio(1);
#pragma unroll
        for (int m = 0; m < 4; ++m)
#pragma unroll
            for (int n = 0; n < 4; ++n)
                acc[m][n] = __builtin_amdgcn_mfma_f32_16x16x32_bf16(af[m], bf[n], acc[m][n], 0, 0, 0);
        __builtin_amdgcn_s_setprio(0);
        __syncthreads();
    }

    size_t zoff = (size_t)z * M * N;
#pragma unroll
    for (int m = 0; m < 4; ++m) {
        int rowb = brow + wr * 64 + m * 16 + (lane >> 4) * 4;
#pragma unroll
        for (int n = 0; n < 4; ++n) {
            int col = bcol + wc * 64 + n * 16 + l15;
            float bv = (z == 0) ? bias[col] : 0.f;
#pragma unroll
            for (int r = 0; r < 4; ++r) {
                float v = acc[m][n][r] + bv;
                size_t idx;
                if (SPLIT) {
                    int mat = col / 768;
                    idx = (size_t)mat * matstride + (size_t)(rowb + r) * 768 + (col - mat * 768);
                } else {
                    idx = zoff + (size_t)(rowb + r) * N + col;
                }
                if (EPI == 0) {
                    ((float*)Cout)[idx] = v;
                } else if (EPI == 1) {
                    ((__hip_bfloat16*)Cout)[idx] = __float2bfloat16(v);
                } else {
                    float g = 0.5f * v * (1.0f + erff(v * 0.70710678118654752f));
                    ((__hip_bfloat16*)Cout)[idx] = __float2bfloat16(g);
                }
            }
        }
    }
}

// ---------------- split-K skinny GEMM: M=6 rows ----------------
__global__ __launch_bounds__(256) void skinny_gemm_k(
    const float* __restrict__ A, const float* __restrict__ W,
    float* __restrict__ partial, int N, int K) {
    __shared__ float Asl[6][64];
    __shared__ float red[4][6][64];
    int tid = threadIdx.x;
    int cl = tid & 63;
    int kg = tid >> 6;
    int col = blockIdx.x * 64 + cl;
    int k0 = blockIdx.y * 64;
    for (int i = tid; i < 6 * 64; i += 256)
        Asl[i >> 6][i & 63] = A[(size_t)(i >> 6) * K + k0 + (i & 63)];
    __syncthreads();
    float acc[6] = {0.f, 0.f, 0.f, 0.f, 0.f, 0.f};
#pragma unroll
    for (int kk = 0; kk < 16; ++kk) {
        int k = kg * 16 + kk;
        float wv = W[(size_t)(k0 + k) * N + col];
#pragma unroll
        for (int m = 0; m < 6; ++m) acc[m] += Asl[m][k] * wv;
    }
#pragma unroll
    for (int m = 0; m < 6; ++m) red[kg][m][cl] = acc[m];
    __syncthreads();
    for (int i = tid; i < 6 * 64; i += 256) {
        int m = i >> 6, lane = i & 63;
        float s = red[0][m][lane] + red[1][m][lane] + red[2][m][lane] + red[3][m][lane];
        partial[(size_t)blockIdx.y * 6 * N + (size_t)m * N + blockIdx.x * 64 + lane] = s;
    }
}

__global__ __launch_bounds__(256) void skinny_reduce_k(
    const float* __restrict__ partial, const float* __restrict__ bias,
    float* __restrict__ outp, int N, int KS, int gelu) {
    int idx = blockIdx.x * 256 + threadIdx.x;
    if (idx >= 6 * N) return;
    int m = idx / N, col = idx - m * N;
    float s = bias[col];
    for (int kb = 0; kb < KS; ++kb)
        s += partial[(size_t)kb * 6 * N + (size_t)m * N + col];
    if (gelu) s = 0.5f * s * (1.0f + erff(s * 0.70710678118654752f));
    outp[(size_t)m * N + col] = s;
}

// ---------------- MFMA sliding-window local attention (128-query blocks) ----------------
__global__ __launch_bounds__(256, 1) void local_attn_k(
    const __hip_bfloat16* __restrict__ Q, const __hip_bfloat16* __restrict__ K,
    const __hip_bfloat16* __restrict__ V, __hip_bfloat16* __restrict__ O) {
    __shared__ __align__(16) __hip_bfloat16 K_lds[64 * 72];
    __shared__ __align__(16) __hip_bfloat16 VT_lds[64 * 72];
    __shared__ __align__(16) __hip_bfloat16 P_lds[4][16 * 72];

    const int cq = blockIdx.x, h = blockIdx.y, b = blockIdx.z;
    const int tid = threadIdx.x;
    const int lane = tid & 63;
    const int w = tid >> 6;
    const int l15 = lane & 15, g4 = lane >> 4;
    const int cbase = cq * QB_;

    frag_ab qf[2][2];
#pragma unroll
    for (int qt = 0; qt < 2; ++qt) {
        int qa = cbase + w * 32 + qt * 16 + l15;
        const __hip_bfloat16* qp = Q + (size_t)(b * S_ + qa) * D_ + h * DH_ + g4 * 8;
        qf[qt][0] = *(const frag_ab*)qp;
        qf[qt][1] = *(const frag_ab*)(qp + 32);
    }

    f32x4 o[2][4];
#pragma unroll
    for (int qt = 0; qt < 2; ++qt)
#pragma unroll
        for (int dt = 0; dt < 4; ++dt) o[qt][dt] = (f32x4){0.f, 0.f, 0.f, 0.f};
    float mrun[2] = {-1e30f, -1e30f};
    float lrun[2] = {0.f, 0.f};

    int kw0 = cbase - W_; if (kw0 < 0) kw0 = 0;
    int kw1 = cbase + QB_ + W_; if (kw1 > S_) kw1 = S_;
    int ntiles = (kw1 - kw0) >> 6;

    char* Pw = (char*)P_lds[w];

    for (int t = 0; t < ntiles; ++t) {
        int k0 = kw0 + t * 64;
        __syncthreads();
        {
            const __hip_bfloat16* Kg = K + (size_t)(b * S_ + k0) * D_ + h * DH_;
            const __hip_bfloat16* Vg = V + (size_t)(b * S_ + k0) * D_ + h * DH_;
#pragma unroll
            for (int it = 0; it < 2; ++it) {
                int idx = tid + it * 256;
                int kk = idx >> 3, d0 = (idx & 7) * 8;
                uint4 kv = *(const uint4*)(Kg + (size_t)kk * D_ + d0);
                *(uint4*)&K_lds[kk * 72 + d0] = kv;
                uint4 vv = *(const uint4*)(Vg + (size_t)kk * D_ + d0);
                unsigned short vs[8];
                *(uint4*)vs = vv;
#pragma unroll
                for (int j = 0; j < 8; ++j) {
                    int dd = d0 + j;
                    int boff = dd * 144 + ((kk * 2) ^ (((dd >> 3) & 7) << 4));
                    *(unsigned short*)((char*)VT_lds + boff) = vs[j];
                }
            }
        }
        __syncthreads();

        frag_ab kf[4][2];
#pragma unroll
        for (int kt = 0; kt < 4; ++kt) {
            const char* kp = (const char*)K_lds + (kt * 16 + l15) * 144 + g4 * 16;
            kf[kt][0] = *(const frag_ab*)kp;
            kf[kt][1] = *(const frag_ab*)(kp + 64);
        }
        frag_ab vf[4][2];
#pragma unroll
        for (int dt = 0; dt < 4; ++dt) {
            int drow = dt * 16 + l15;
            int swz = ((drow >> 3) & 7) << 4;
            const char* vp = (const char*)VT_lds + drow * 144;
            vf[dt][0] = *(const frag_ab*)(vp + ((g4 * 16) ^ swz));
            vf[dt][1] = *(const frag_ab*)(vp + ((g4 * 16 + 64) ^ swz));
        }

#pragma unroll
        for (int qt = 0; qt < 2; ++qt) {
            f32x4 st[4];
            __builtin_amdgcn_s_setprio(1);
#pragma unroll
            for (int kt = 0; kt < 4; ++kt) {
                f32x4 z = (f32x4){0.f, 0.f, 0.f, 0.f};
                z = __builtin_amdgcn_mfma_f32_16x16x32_bf16(kf[kt][0], qf[qt][0], z, 0, 0, 0);
                z = __builtin_amdgcn_mfma_f32_16x16x32_bf16(kf[kt][1], qf[qt][1], z, 0, 0, 0);
                st[kt] = z;
            }
            __builtin_amdgcn_s_setprio(0);
            int qa = cbase + w * 32 + qt * 16 + l15;
            float sv[16];
            float mx = -1e30f;
#pragma unroll
            for (int kt = 0; kt < 4; ++kt)
#pragma unroll
                for (int r = 0; r < 4; ++r) {
                    int ka = k0 + kt * 16 + g4 * 4 + r;
                    float s = st[kt][r] * 0.125f;
                    bool bad = (ka < NG_) | (ka - qa > W_) | (qa - ka > W_);
                    s = bad ? -1e30f : s;
                    sv[kt * 4 + r] = s;
                    mx = fmaxf(mx, s);
                }
            mx = fmaxf(mx, __shfl_xor(mx, 16));
            mx = fmaxf(mx, __shfl_xor(mx, 32));
            float mnew = fmaxf(fmaxf(mrun[qt], mx), -60.0f);
            if (__any(mnew != mrun[qt])) {
                float fsc = __expf(mrun[qt] - mnew);
                mrun[qt] = mnew;
#pragma unroll
                for (int dt = 0; dt < 4; ++dt) o[qt][dt] *= fsc;
                lrun[qt] *= fsc;
            }
            float psum = 0.f;
            unsigned short pb[16];
#pragma unroll
            for (int i = 0; i < 16; ++i) {
                float p = __expf(sv[i] - mrun[qt]);
                psum += p;
                pb[i] = f2bfu(p);
            }
            psum += __shfl_xor(psum, 16);
            psum += __shfl_xor(psum, 32);
            lrun[qt] += psum;
#pragma unroll
            for (int kt = 0; kt < 4; ++kt)
#pragma unroll
                for (int rp = 0; rp < 2; ++rp) {
                    unsigned vpk = (unsigned)pb[kt * 4 + rp * 2] | ((unsigned)pb[kt * 4 + rp * 2 + 1] << 16);
                    int kloc = kt * 16 + g4 * 4 + rp * 2;
                    *(unsigned*)(Pw + l15 * 144 + kloc * 2) = vpk;
                }
            frag_ab pf0 = *(const frag_ab*)(Pw + l15 * 144 + g4 * 16);
            frag_ab pf1 = *(const frag_ab*)(Pw + l15 * 144 + g4 * 16 + 64);
            __builtin_amdgcn_s_setprio(1);
#pragma unroll
            for (int dt = 0; dt < 4; ++dt) {
                o[qt][dt] = __builtin_amdgcn_mfma_f32_16x16x32_bf16(vf[dt][0], pf0, o[qt][dt], 0, 0, 0);
                o[qt][dt] = __builtin_amdgcn_mfma_f32_16x16x32_bf16(vf[dt][1], pf1, o[qt][dt], 0, 0, 0);
            }
            __builtin_amdgcn_s_setprio(0);
        }
    }

    // ---- 3 global keys (unmasked), scalar epilogue ----
    uint4 kgc[3][2];
    uint2 vgd[3][4];
#pragma unroll
    for (int gk = 0; gk < NG_; ++gk) {
        const __hip_bfloat16* kp = K + (size_t)(b * S_ + gk) * D_ + h * DH_ + g4 * 8;
        kgc[gk][0] = *(const uint4*)kp;
        kgc[gk][1] = *(const uint4*)(kp + 32);
        const __hip_bfloat16* vp = V + (size_t)(b * S_ + gk) * D_ + h * DH_ + g4 * 4;
#pragma unroll
        for (int dt = 0; dt < 4; ++dt)
            vgd[gk][dt] = *(const uint2*)(vp + dt * 16);
    }
#pragma unroll
    for (int qt = 0; qt < 2; ++qt) {
        float sg[3];
#pragma unroll
        for (int gk = 0; gk < NG_; ++gk) {
            float part = 0.f;
#pragma unroll
            for (int s = 0; s < 2; ++s) {
                uint4 qw = *(uint4*)&qf[qt][s];
                uint4 kw = kgc[gk][s];
                part += bflo(qw.x) * bflo(kw.x) + bfhi(qw.x) * bfhi(kw.x);
                part += bflo(qw.y) * bflo(kw.y) + bfhi(qw.y) * bfhi(kw.y);
                part += bflo(qw.z) * bflo(kw.z) + bfhi(qw.z) * bfhi(kw.z);
                part += bflo(qw.w) * bflo(kw.w) + bfhi(qw.w) * bfhi(kw.w);
            }
            part += __shfl_xor(part, 16);
            part += __shfl_xor(part, 32);
            sg[gk] = part * 0.125f;
        }
        float mx3 = fmaxf(fmaxf(sg[0], sg[1]), sg[2]);
        float mnew = fmaxf(fmaxf(mrun[qt], mx3), -60.0f);
        float fsc = __expf(mrun[qt] - mnew);
        mrun[qt] = mnew;
#pragma unroll
        for (int dt = 0; dt < 4; ++dt) o[qt][dt] *= fsc;
        lrun[qt] *= fsc;
        float pg[3];
        float psum = 0.f;
#pragma unroll
        for (int gk = 0; gk < NG_; ++gk) { pg[gk] = __expf(sg[gk] - mnew); psum += pg[gk]; }
        lrun[qt] += psum;
#pragma unroll
        for (int dt = 0; dt < 4; ++dt) {
#pragma unroll
            for (int gk = 0; gk < NG_; ++gk) {
                uint2 vv = vgd[gk][dt];
                o[qt][dt][0] += pg[gk] * bflo(vv.x);
                o[qt][dt][1] += pg[gk] * bfhi(vv.x);
                o[qt][dt][2] += pg[gk] * bflo(vv.y);
                o[qt][dt][3] += pg[gk] * bfhi(vv.y);
            }
        }
    }

#pragma unroll
    for (int qt = 0; qt < 2; ++qt) {
        float linv = 1.0f / lrun[qt];
        int qa = cbase + w * 32 + qt * 16 + l15;
        __hip_bfloat16* orow = O + (size_t)(b * S_ + qa) * D_ + h * DH_;
#pragma unroll
        for (int dt = 0; dt < 4; ++dt) {
            unsigned short pk[4];
#pragma unroll
            for (int r = 0; r < 4; ++r) pk[r] = f2bfu(o[qt][dt][r] * linv);
            *(uint2*)(orow + dt * 16 + g4 * 4) = *(uint2*)pk;
        }
    }
}

// ---------------- global attention, split-S flash decode ----------------
__global__ __launch_bounds__(256) void gattn_part_k(
    const float* __restrict__ qg, const __hip_bfloat16* __restrict__ KG,
    const __hip_bfloat16* __restrict__ VG, float* __restrict__ gpart) {
    __shared__ float sc[256];
    __shared__ float qs[DH_];
    __shared__ float red[256];
    __shared__ float rv[16][64];
    int split = blockIdx.x;
    int gh = blockIdx.y;
    int g = gh / H_, h = gh - g * H_;
    int b = blockIdx.z;
    int tid = threadIdx.x;
    if (tid < DH_) qs[tid] = qg[(size_t)(b * NG_ + g) * D_ + h * DH_ + tid] * 0.125f;
    __syncthreads();
    int s0 = split * (S_ / NSPLIT_);
    float acc = 0.f;
    {
        const __hip_bfloat16* kp = KG + (size_t)(b * S_ + s0 + tid) * D_ + h * DH_;
#pragma unroll
        for (int c8 = 0; c8 < 8; ++c8) {
            uint4 t = *(const uint4*)(kp + c8 * 8);
            float f[8]; unp8(t, f);
#pragma unroll
            for (int j = 0; j < 8; ++j) acc += qs[c8 * 8 + j] * f[j];
        }
    }
    float m = block_max(acc, red);
    float e = __expf(acc - m);
    sc[tid] = e;
    float l = block_sum(e, red);
    int sgq = tid >> 4, dq = (tid & 15) * 4;
    float a0 = 0.f, a1 = 0.f, a2 = 0.f, a3 = 0.f;
    const __hip_bfloat16* vbase = VG + (size_t)(b * S_ + s0 + sgq * 16) * D_ + h * DH_ + dq;
#pragma unroll
    for (int i = 0; i < 16; ++i) {
        float p = sc[sgq * 16 + i];
        uint2 vv = *(const uint2*)(vbase + (size_t)i * D_);
        a0 += p * bflo(vv.x); a1 += p * bfhi(vv.x);
        a2 += p * bflo(vv.y); a3 += p * bfhi(vv.y);
    }
    rv[sgq][dq] = a0; rv[sgq][dq + 1] = a1; rv[sgq][dq + 2] = a2; rv[sgq][dq + 3] = a3;
    __syncthreads();
    float* op = gpart + ((size_t)((b * NG_ + g) * H_ + h) * NSPLIT_ + split) * 66;
    if (tid == 0) { op[0] = m; op[1] = l; }
    if (tid < DH_) {
        float s = 0.f;
#pragma unroll
        for (int j = 0; j < 16; ++j) s += rv[j][tid];
        op[2 + tid] = s;
    }
}

template <typename TO>
__global__ __launch_bounds__(64) void gattn_comb_k(
    const float* __restrict__ gpart, TO* __restrict__ outp, int rowStride) {
    int g = blockIdx.x, h = blockIdx.y, b = blockIdx.z;
    int tid = threadIdx.x;
    const float* base = gpart + (size_t)((b * NG_ + g) * H_ + h) * NSPLIT_ * 66;
    float M = -1e30f;
#pragma unroll
    for (int p = 0; p < NSPLIT_; ++p) M = fmaxf(M, base[p * 66]);
    float l = 0.f, o = 0.f;
#pragma unroll
    for (int p = 0; p < NSPLIT_; ++p) {
        float wgt = __expf(base[p * 66] - M);
        l += wgt * base[p * 66 + 1];
        o += wgt * base[p * 66 + 2 + tid];
    }
    storeO(&outp[(size_t)(b * rowStride + g) * D_ + h * DH_ + tid], o / l);
}

// ---------------- gather the 6 global-token rows ----------------
__global__ void gather6_k(const float* __restrict__ X, float* __restrict__ xg) {
    int r = blockIdx.x;
    int b = r / NG_, g = r % NG_;
    for (int c = threadIdx.x; c < D_; c += blockDim.x)
        xg[(size_t)r * D_ + c] = X[(size_t)(b * S_ + g) * D_ + c];
}

// ---------------- classifier heads ----------------
__global__ __launch_bounds__(256) void classifier_k(
    const float* __restrict__ x26, const float* __restrict__ cw,
    const float* __restrict__ cb, float* __restrict__ out) {
    __shared__ float red[256];
    int tid = threadIdx.x;
    for (int i = 0; i < 3; ++i) {
        for (int b = 0; b < B_; ++b) {
            const float* xr = x26 + (size_t)(b * NG_ + i) * D_;
            const float* wr = cw + (size_t)i * D_;
            float p = 0.f;
            for (int c = tid; c < D_; c += 256) p += xr[c] * wr[c];
            float dotv = block_sum(p, red);
            if (tid == 0) out[i * B_ + b] = 1.0f / (1.0f + __expf(-(dotv + cb[i])));
        }
    }
    if (tid == 0) { out[6] = 1.0f; out[7] = 1.0f; }
}

// ---------------- host launcher ----------------
extern "C" void kernel_launch(void* const* d_in, const int* in_sizes, int n_in,
                              void* d_out, int out_size, void* d_ws, size_t ws_size,
                              hipStream_t stream) {
    const int*   src      = (const int*)d_in[0];
    const float* word_emb = (const float*)d_in[3];
    const float* pos_emb  = (const float*)d_in[4];
    const float* emb_ln   = (const float*)d_in[5];
    const float* attn_w   = (const float*)d_in[6];
    const float* attn_b   = (const float*)d_in[7];
    const float* ln_p     = (const float*)d_in[8];
    const float* ffn_w1   = (const float*)d_in[9];
    const float* ffn_b1   = (const float*)d_in[10];
    const float* ffn_w2   = (const float*)d_in[11];
    const float* ffn_b2   = (const float*)d_in[12];
    const float* cls_w    = (const float*)d_in[13];
    const float* cls_b    = (const float*)d_in[14];
    float* out = (float*)d_out;

    const size_t NT = (size_t)B_ * S_ * D_;  // 6291456 elements
    // -------- workspace layout (floats), NO overlaps --------
    float* base = (float*)d_ws;
    float* X  = base;
    float* P4 = base + NT;
    __hip_bfloat16* Xb  = (__hip_bfloat16*)(base + 2 * NT);
    __hip_bfloat16* Qb  = (__hip_bfloat16*)(base + 5 * NT / 2);
    __hip_bfloat16* Kb  = (__hip_bfloat16*)(base + 3 * NT);
    __hip_bfloat16* Vb  = (__hip_bfloat16*)(base + 7 * NT / 2);
    __hip_bfloat16* KGb = (__hip_bfloat16*)(base + 4 * NT);
    __hip_bfloat16* VGb = (__hip_bfloat16*)(base + 9 * NT / 2);
    __hip_bfloat16* AOb = (__hip_bfloat16*)(base + 5 * NT);
    __hip_bfloat16* HCb = (__hip_bfloat16*)(base + 11 * NT / 2);   // 2NT floats
    float* pj1 = base + 15 * NT / 2;
    float* pj2 = base + 17 * NT / 2;
    __hip_bfloat16* wq5 = (__hip_bfloat16*)(base + 19 * NT / 2);   // 5 x 768x768
    __hip_bfloat16* wo  = wq5 + 5 * 589824;
    __hip_bfloat16* wg1 = wo + 589824;                  // layer-1 kg/vg pair
    __hip_bfloat16* wf1 = wg1 + 2 * 589824;             // 3072x768
    __hip_bfloat16* wf2 = wf1 + 2359296;                // 768x3072
    float* SM  = (float*)(wf2 + 2359296);
    float* xg  = SM;
    float* qg6 = xg + 6 * D_;
    float* og6 = qg6 + 6 * D_;
    float* pr6 = og6 + 6 * D_;
    float* xa6 = pr6 + 6 * D_;
    float* h6  = xa6 + 6 * D_;
    float* f6  = h6 + 6 * FF_;
    float* x26 = f6 + 6 * D_;
    float* bias5 = x26 + 6 * D_;        // 3840
    float* part = bias5 + 5 * D_;       // split-K skinny partials
    float* gpart = part;                // aliased (never live simultaneously)

    const int M = B_ * S_;
    dim3 blk(256);

    auto aw = [&](int l, int i) { return attn_w + ((size_t)(l * 7 + i)) * D_ * D_; };
    auto ab = [&](int l, int i) { return attn_b + (size_t)(l * 7 + i) * D_; };
    auto lnp = [&](int l, int i) { return ln_p + (size_t)(l * 4 + i) * D_; };

    auto skinny = [&](const float* A6, const float* Wm, const float* bias,
                      float* out6, int N, int K, int gelu) {
        skinny_gemm_k<<<dim3(N / 64, K / 64), blk, 0, stream>>>(A6, Wm, part, N, K);
        skinny_reduce_k<<<dim3((6 * N + 255) / 256), blk, 0, stream>>>(part, bias, out6, N, K / 64, gelu);
    };

    embed_ln_k<<<M, blk, 0, stream>>>(src, word_emb, pos_emb, emb_ln, emb_ln + D_, X, Xb);

    // ================= layer 0 =================
    // mega projection: [Q,K,V,KG,VG] = Xb @ [wq wk wv wg1 wg2]^T  (N=3840)
    convt_k<<<dim3(24 * 3, 24), blk, 0, stream>>>(aw(0, 0), wq5, D_, D_, 24);
    convt_k<<<dim3(24 * 2, 24), blk, 0, stream>>>(aw(0, 4), wq5 + 3 * 589824, D_, D_, 24);
    pack_bias_k<<<15, blk, 0, stream>>>(ab(0, 0), bias5);
    mfma_gemm_k<1, 1><<<dim3(3840 / 128, 64), blk, 0, stream>>>(Xb, wq5, bias5, Qb, M, 3840, D_, NT);
    local_attn_k<<<dim3(S_ / QB_, H_, B_), blk, 0, stream>>>(Qb, Kb, Vb, AOb);
    gather6_k<<<B_ * NG_, blk, 0, stream>>>(X, xg);
    skinny(xg, aw(0, 3), ab(0, 3), qg6, D_, D_, 0);
    gattn_part_k<<<dim3(NSPLIT_, NG_ * H_, B_), blk, 0, stream>>>(qg6, KGb, VGb, gpart);
    gattn_comb_k<__hip_bfloat16><<<dim3(NG_, H_, B_), dim3(64), 0, stream>>>(gpart, AOb, S_);
    // attn output projection, split-K x2 -> pj1/pj2, combined in residual LN
    convt_k<<<dim3(24, 24), blk, 0, stream>>>(aw(0, 6), wo, D_, D_, 24);
    mfma_gemm_k<0, 0><<<dim3(6, 64, 2), blk, 0, stream>>>(AOb, wo, ab(0, 6), pj1, M, D_, D_, 0);
    residual_ln_k<<<M, blk, 0, stream>>>(X, pj1, pj2, lnp(0, 0), lnp(0, 1), P4, Xb);
    // FFN (full-M)
    convt_k<<<dim3(96, 24), blk, 0, stream>>>(ffn_w1, wf1, D_, FF_, 96);
    convt_k<<<dim3(24, 96), blk, 0, stream>>>(ffn_w2, wf2, FF_, D_, 24);
    mfma_gemm_k<2, 0><<<dim3(24, 64), blk, 0, stream>>>(Xb, wf1, ffn_b1, HCb, M, FF_, D_, 0);
    mfma_gemm_k<0, 0><<<dim3(6, 64, 2), blk, 0, stream>>>(HCb, wf2, ffn_b2, pj1, M, D_, FF_, 0);
    residual_ln_k<<<M, blk, 0, stream>>>(P4, pj1, pj2, lnp(0, 2), lnp(0, 3), X, Xb);

    // ================= layer 1 (pruned) =================
    convt_k<<<dim3(24 * 2, 24), blk, 0, stream>>>(aw(1, 4), wg1, D_, D_, 24);
    mfma_gemm_k<1, 1><<<dim3(1536 / 128, 64), blk, 0, stream>>>(Xb, wg1, ab(1, 4), KGb, M, 1536, D_, NT);
    gather6_k<<<B_ * NG_, blk, 0, stream>>>(X, xg);
    skinny(xg, aw(1, 3), ab(1, 3), qg6, D_, D_, 0);
    gattn_part_k<<<dim3(NSPLIT_, NG_ * H_, B_), blk, 0, stream>>>(qg6, KGb, VGb, gpart);
    gattn_comb_k<float><<<dim3(NG_, H_, B_), dim3(64), 0, stream>>>(gpart, og6, NG_);
    skinny(og6, aw(1, 6), ab(1, 6), pr6, D_, D_, 0);
    residual_ln_k<<<B_ * NG_, blk, 0, stream>>>(xg, pr6, nullptr, lnp(1, 0), lnp(1, 1), xa6, nullptr);
    skinny(xa6, ffn_w1 + (size_t)D_ * FF_, ffn_b1 + FF_, h6, FF_, D_, 1);
    skinny(h6, ffn_w2 + (size_t)FF_ * D_, ffn_b2 + D_, f6, D_, FF_, 0);
    residual_ln_k<<<B_ * NG_, blk, 0, stream>>>(xa6, f6, nullptr, lnp(1, 2), lnp(1, 3), x26, nullptr);
    classifier_k<<<1, blk, 0, stream>>>(x26, cls_w, cls_b, out);
}

// Round 13
// 504.910 us; speedup vs baseline: 1.0243x; 1.0243x over previous
//
#include <hip/hip_runtime.h>
#include <hip/hip_bf16.h>
#include <math.h>

// ---------------- constants (problem shapes) ----------------
#define B_    2
#define SSRC_ 4093
#define D_    768
#define H_    12
#define DH_   64
#define FF_   3072
#define NG_   3
#define W_    256
#define S_    4096
#define NC_   16
#define NSPLIT_ 16
#define QB_   128

typedef __attribute__((ext_vector_type(8))) short frag_ab;   // 8 bf16 (4 VGPRs)
typedef __attribute__((ext_vector_type(4))) float f32x4;     // 4 fp32 acc

// async global->LDS, 16B per lane (linear dest: base + lane*16)
#define GL16(gp, lp) __builtin_amdgcn_global_load_lds( \
    (const __attribute__((address_space(1))) void*)(gp), \
    (__attribute__((address_space(3))) void*)(lp), 16, 0, 0)

// ---------------- helpers ----------------
__device__ __forceinline__ float bflo(unsigned int w) {
    union { float f; unsigned int i; } c; c.i = w << 16; return c.f;
}
__device__ __forceinline__ float bfhi(unsigned int w) {
    union { float f; unsigned int i; } c; c.i = w & 0xffff0000u; return c.f;
}
__device__ __forceinline__ void unp8(uint4 t, float* o) {
    o[0] = bflo(t.x); o[1] = bfhi(t.x); o[2] = bflo(t.y); o[3] = bfhi(t.y);
    o[4] = bflo(t.z); o[5] = bfhi(t.z); o[6] = bflo(t.w); o[7] = bfhi(t.w);
}
__device__ __forceinline__ unsigned short f2bfu(float x) {
    __hip_bfloat16 h = __float2bfloat16(x);
    return *reinterpret_cast<unsigned short*>(&h);
}

__device__ __forceinline__ float block_sum(float v, float* red) {
    int tid = threadIdx.x;
    red[tid] = v;
    __syncthreads();
#pragma unroll
    for (int off = 128; off >= 1; off >>= 1) {
        if (tid < off) red[tid] += red[tid + off];
        __syncthreads();
    }
    float r = red[0];
    __syncthreads();
    return r;
}

__device__ __forceinline__ float block_max(float v, float* red) {
    int tid = threadIdx.x;
    red[tid] = v;
    __syncthreads();
#pragma unroll
    for (int off = 128; off >= 1; off >>= 1) {
        if (tid < off) red[tid] = fmaxf(red[tid], red[tid + off]);
        __syncthreads();
    }
    float r = red[0];
    __syncthreads();
    return r;
}

__device__ __forceinline__ void storeO(float* p, float v) { *p = v; }
__device__ __forceinline__ void storeO(__hip_bfloat16* p, float v) { *p = __float2bfloat16(v); }

// ---------------- embedding + LN (writes f32 X and bf16 Xb) ----------------
__global__ __launch_bounds__(256) void embed_ln_k(
    const int* __restrict__ src, const float* __restrict__ we,
    const float* __restrict__ pe, const float* __restrict__ gam,
    const float* __restrict__ bet, float* __restrict__ X,
    __hip_bfloat16* __restrict__ Xb) {
    __shared__ float red[256];
    int row = blockIdx.x;
    int b = row >> 12;
    int s = row & (S_ - 1);
    int tid = threadIdx.x;
    int id = (s < NG_) ? (50261 + s) : src[b * SSRC_ + (s - NG_)];
    const float* wr = we + (size_t)id * D_;
    const float* pr = pe + (size_t)s * D_;
    float v[3];
    float lsum = 0.f;
#pragma unroll
    for (int j = 0; j < 3; ++j) {
        int c = tid + j * 256;
        v[j] = wr[c] + pr[c];
        lsum += v[j];
    }
    float mu = block_sum(lsum, red) * (1.0f / 768.0f);
    float ls2 = 0.f;
#pragma unroll
    for (int j = 0; j < 3; ++j) { float d = v[j] - mu; ls2 += d * d; }
    float var = block_sum(ls2, red) * (1.0f / 768.0f);
    float rs = rsqrtf(var + 1e-5f);
    float* xr = X + (size_t)row * D_;
    __hip_bfloat16* xbr = Xb + (size_t)row * D_;
#pragma unroll
    for (int j = 0; j < 3; ++j) {
        int c = tid + j * 256;
        float o = (v[j] - mu) * rs * gam[c] + bet[c];
        xr[c] = o;
        xbr[c] = __float2bfloat16(o);
    }
}

// ---------------- residual + LN : out = LN(x + y [+ y2]), optional bf16 mirror ----------------
__global__ __launch_bounds__(256) void residual_ln_k(
    const float* __restrict__ x, const float* __restrict__ y,
    const float* __restrict__ y2, const float* __restrict__ gam,
    const float* __restrict__ bet, float* __restrict__ out,
    __hip_bfloat16* __restrict__ outb) {
    __shared__ float red[256];
    int row = blockIdx.x;
    int tid = threadIdx.x;
    const float* xr = x + (size_t)row * D_;
    const float* yr = y + (size_t)row * D_;
    const float* y2r = y2 ? y2 + (size_t)row * D_ : nullptr;
    float v[3];
    float lsum = 0.f;
#pragma unroll
    for (int j = 0; j < 3; ++j) {
        int c = tid + j * 256;
        v[j] = xr[c] + yr[c];
        if (y2r) v[j] += y2r[c];
        lsum += v[j];
    }
    float mu = block_sum(lsum, red) * (1.0f / 768.0f);
    float ls2 = 0.f;
#pragma unroll
    for (int j = 0; j < 3; ++j) { float d = v[j] - mu; ls2 += d * d; }
    float var = block_sum(ls2, red) * (1.0f / 768.0f);
    float rs = rsqrtf(var + 1e-5f);
    float* orow = out + (size_t)row * D_;
    __hip_bfloat16* obr = outb ? outb + (size_t)row * D_ : nullptr;
#pragma unroll
    for (int j = 0; j < 3; ++j) {
        int c = tid + j * 256;
        float o = (v[j] - mu) * rs * gam[c] + bet[c];
        orow[c] = o;
        if (obr) obr[c] = __float2bfloat16(o);
    }
}

// ---------------- transpose-convert: nmat x (W[K,N] f32 -> WT[N,K] bf16) ----------------
__global__ __launch_bounds__(256) void convt_k(
    const float* __restrict__ W, __hip_bfloat16* __restrict__ WT,
    int K, int N, int npb /* = N/32 */) {
    __shared__ float tile[32][33];
    int mat = blockIdx.x / npb;
    int bx = blockIdx.x - mat * npb;
    int by = blockIdx.y;
    const float* Wm = W + (size_t)mat * K * N;
    __hip_bfloat16* WTm = WT + (size_t)mat * N * K;
    int tx = threadIdx.x & 31, ty = threadIdx.x >> 5;
#pragma unroll
    for (int i = 0; i < 32; i += 8)
        tile[ty + i][tx] = Wm[(size_t)(by * 32 + ty + i) * N + bx * 32 + tx];
    __syncthreads();
#pragma unroll
    for (int i = 0; i < 32; i += 8)
        WTm[(size_t)(bx * 32 + ty + i) * K + by * 32 + tx] = __float2bfloat16(tile[tx][ty + i]);
}

// ---------------- pack layer-0 mega bias: [ab0,ab1,ab2,ab4,ab5] -> 3840 ----------------
__global__ void pack_bias_k(const float* __restrict__ ab, float* __restrict__ dst) {
    int j = blockIdx.x * 256 + threadIdx.x;
    if (j >= 5 * 768) return;
    int mat = j / 768, c = j - mat * 768;
    int i = (mat < 3) ? mat : mat + 1;
    dst[j] = ab[i * 768 + c];
}

// ---------------- MFMA GEMM (2-phase double-buffered pipeline, T3 minimum) ----------------
// C[M,N] = A[M,K]bf16 @ BT[N,K]^T + bias
// Pipeline: STAGE(next tile) issued BEFORE ds_read+MFMA of current tile; single
// __syncthreads per iter (drains vmcnt -> next buffer ready, and gates buffer reuse).
// XCD-chunked block swizzle (bijective when nwg%8==0).
// EPI: 0 = f32 out, 1 = bf16 out, 2 = bf16 gelu(out)
// SPLIT: 1 => output col c -> matrix c/768 (stride matstride bf16 elems)
// gridDim.z > 1 => split-K: z-th K-slice, f32 partial at Cout + z*M*N (EPI must be 0)
template <int EPI, int SPLIT>
__global__ __launch_bounds__(256) void mfma_gemm_k(
    const __hip_bfloat16* __restrict__ A, const __hip_bfloat16* __restrict__ BT,
    const float* __restrict__ bias, void* __restrict__ Cout,
    int M, int N, int K, size_t matstride) {
    __shared__ __align__(16) __hip_bfloat16 As[2][4096];
    __shared__ __align__(16) __hip_bfloat16 Bs[2][4096];
    int tid = threadIdx.x;
    int lane = tid & 63;
    int w = tid >> 6, wr = w >> 1, wc = w & 1;
    // XCD-chunked swizzle over the x-y grid (same-XCD blocks get contiguous ids)
    int nwg = gridDim.x * gridDim.y;
    int id = blockIdx.y * gridDim.x + blockIdx.x;
    if ((nwg & 7) == 0) {
        int per = nwg >> 3;
        id = (id & 7) * per + (id >> 3);
    }
    int bx = id % gridDim.x, by = id / gridDim.x;
    int brow = by * 128, bcol = bx * 128;
    int z = blockIdx.z, nz = gridDim.z;
    int Kz = K / nz;
    int r0 = tid >> 2, k0 = (tid & 3) * 8;
    const __hip_bfloat16* Ag0 = A + (size_t)(brow + r0) * K + z * Kz + k0;
    const __hip_bfloat16* Ag1 = Ag0 + (size_t)64 * K;
    const __hip_bfloat16* Bg0 = BT + (size_t)(bcol + r0) * K + z * Kz + k0;
    const __hip_bfloat16* Bg1 = Bg0 + (size_t)64 * K;

    f32x4 acc[4][4];
#pragma unroll
    for (int m = 0; m < 4; ++m)
#pragma unroll
        for (int n = 0; n < 4; ++n) acc[m][n] = (f32x4){0.f, 0.f, 0.f, 0.f};

    int l15 = lane & 15, kb = lane >> 4;
    int aoff = (wr * 64 + l15) * 32 + kb * 8;
    int boff = (wc * 64 + l15) * 32 + kb * 8;

    int nt = Kz >> 5;
    // prologue: stage tile 0 into buffer 0
    GL16(Ag0, &As[0][tid * 8]);
    GL16(Ag1, &As[0][tid * 8 + 2048]);
    GL16(Bg0, &Bs[0][tid * 8]);
    GL16(Bg1, &Bs[0][tid * 8 + 2048]);
    __syncthreads();

    for (int t = 0; t < nt; ++t) {
        int cur = t & 1;
        if (t + 1 < nt) {   // issue next-tile stage BEFORE compute (latency hides under MFMA)
            int nxt = cur ^ 1;
            int kt = (t + 1) << 5;
            GL16(Ag0 + kt, &As[nxt][tid * 8]);
            GL16(Ag1 + kt, &As[nxt][tid * 8 + 2048]);
            GL16(Bg0 + kt, &Bs[nxt][tid * 8]);
            GL16(Bg1 + kt, &Bs[nxt][tid * 8 + 2048]);
        }
        frag_ab af[4], bf[4];
#pragma unroll
        for (int m = 0; m < 4; ++m) af[m] = *(const frag_ab*)&As[cur][aoff + m * 512];
#pragma unroll
        for (int n = 0; n < 4; ++n) bf[n] = *(const frag_ab*)&Bs[cur][boff + n * 512];
        __builtin_amdgcn_s_setprio(1);
#pragma unroll
        for (int m = 0; m < 4; ++m)
#pragma unroll
            for (int n = 0; n < 4; ++n)
                acc[m][n] = __builtin_amdgcn_mfma_f32_16x16x32_bf16(af[m], bf[n], acc[m][n], 0, 0, 0);
        __builtin_amdgcn_s_setprio(0);
        __syncthreads();   // drains vmcnt (next buf ready) + all waves done reading cur buf
    }

    size_t zoff = (size_t)z * M * N;
#pragma unroll
    for (int m = 0; m < 4; ++m) {
        int rowb = brow + wr * 64 + m * 16 + (lane >> 4) * 4;
#pragma unroll
        for (int n = 0; n < 4; ++n) {
            int col = bcol + wc * 64 + n * 16 + l15;
            float bv = (z == 0) ? bias[col] : 0.f;
#pragma unroll
            for (int r = 0; r < 4; ++r) {
                float v = acc[m][n][r] + bv;
                size_t idx;
                if (SPLIT) {
                    int mat = col / 768;
                    idx = (size_t)mat * matstride + (size_t)(rowb + r) * 768 + (col - mat * 768);
                } else {
                    idx = zoff + (size_t)(rowb + r) * N + col;
                }
                if (EPI == 0) {
                    ((float*)Cout)[idx] = v;
                } else if (EPI == 1) {
                    ((__hip_bfloat16*)Cout)[idx] = __float2bfloat16(v);
                } else {
                    float g = 0.5f * v * (1.0f + erff(v * 0.70710678118654752f));
                    ((__hip_bfloat16*)Cout)[idx] = __float2bfloat16(g);
                }
            }
        }
    }
}

// ---------------- split-K skinny GEMM: M=6 rows ----------------
__global__ __launch_bounds__(256) void skinny_gemm_k(
    const float* __restrict__ A, const float* __restrict__ W,
    float* __restrict__ partial, int N, int K) {
    __shared__ float Asl[6][64];
    __shared__ float red[4][6][64];
    int tid = threadIdx.x;
    int cl = tid & 63;
    int kg = tid >> 6;
    int col = blockIdx.x * 64 + cl;
    int k0 = blockIdx.y * 64;
    for (int i = tid; i < 6 * 64; i += 256)
        Asl[i >> 6][i & 63] = A[(size_t)(i >> 6) * K + k0 + (i & 63)];
    __syncthreads();
    float acc[6] = {0.f, 0.f, 0.f, 0.f, 0.f, 0.f};
#pragma unroll
    for (int kk = 0; kk < 16; ++kk) {
        int k = kg * 16 + kk;
        float wv = W[(size_t)(k0 + k) * N + col];
#pragma unroll
        for (int m = 0; m < 6; ++m) acc[m] += Asl[m][k] * wv;
    }
#pragma unroll
    for (int m = 0; m < 6; ++m) red[kg][m][cl] = acc[m];
    __syncthreads();
    for (int i = tid; i < 6 * 64; i += 256) {
        int m = i >> 6, lane = i & 63;
        float s = red[0][m][lane] + red[1][m][lane] + red[2][m][lane] + red[3][m][lane];
        partial[(size_t)blockIdx.y * 6 * N + (size_t)m * N + blockIdx.x * 64 + lane] = s;
    }
}

__global__ __launch_bounds__(256) void skinny_reduce_k(
    const float* __restrict__ partial, const float* __restrict__ bias,
    float* __restrict__ outp, int N, int KS, int gelu) {
    int idx = blockIdx.x * 256 + threadIdx.x;
    if (idx >= 6 * N) return;
    int m = idx / N, col = idx - m * N;
    float s = bias[col];
    for (int kb = 0; kb < KS; ++kb)
        s += partial[(size_t)kb * 6 * N + (size_t)m * N + col];
    if (gelu) s = 0.5f * s * (1.0f + erff(s * 0.70710678118654752f));
    outp[(size_t)m * N + col] = s;
}

// ---------------- MFMA sliding-window local attention (128-query blocks) ----------------
__global__ __launch_bounds__(256, 1) void local_attn_k(
    const __hip_bfloat16* __restrict__ Q, const __hip_bfloat16* __restrict__ K,
    const __hip_bfloat16* __restrict__ V, __hip_bfloat16* __restrict__ O) {
    __shared__ __align__(16) __hip_bfloat16 K_lds[64 * 72];
    __shared__ __align__(16) __hip_bfloat16 VT_lds[64 * 72];
    __shared__ __align__(16) __hip_bfloat16 P_lds[4][16 * 72];

    const int cq = blockIdx.x, h = blockIdx.y, b = blockIdx.z;
    const int tid = threadIdx.x;
    const int lane = tid & 63;
    const int w = tid >> 6;
    const int l15 = lane & 15, g4 = lane >> 4;
    const int cbase = cq * QB_;

    frag_ab qf[2][2];
#pragma unroll
    for (int qt = 0; qt < 2; ++qt) {
        int qa = cbase + w * 32 + qt * 16 + l15;
        const __hip_bfloat16* qp = Q + (size_t)(b * S_ + qa) * D_ + h * DH_ + g4 * 8;
        qf[qt][0] = *(const frag_ab*)qp;
        qf[qt][1] = *(const frag_ab*)(qp + 32);
    }

    f32x4 o[2][4];
#pragma unroll
    for (int qt = 0; qt < 2; ++qt)
#pragma unroll
        for (int dt = 0; dt < 4; ++dt) o[qt][dt] = (f32x4){0.f, 0.f, 0.f, 0.f};
    float mrun[2] = {-1e30f, -1e30f};
    float lrun[2] = {0.f, 0.f};

    int kw0 = cbase - W_; if (kw0 < 0) kw0 = 0;
    int kw1 = cbase + QB_ + W_; if (kw1 > S_) kw1 = S_;
    int ntiles = (kw1 - kw0) >> 6;

    char* Pw = (char*)P_lds[w];

    for (int t = 0; t < ntiles; ++t) {
        int k0 = kw0 + t * 64;
        __syncthreads();
        {
            const __hip_bfloat16* Kg = K + (size_t)(b * S_ + k0) * D_ + h * DH_;
            const __hip_bfloat16* Vg = V + (size_t)(b * S_ + k0) * D_ + h * DH_;
#pragma unroll
            for (int it = 0; it < 2; ++it) {
                int idx = tid + it * 256;
                int kk = idx >> 3, d0 = (idx & 7) * 8;
                uint4 kv = *(const uint4*)(Kg + (size_t)kk * D_ + d0);
                *(uint4*)&K_lds[kk * 72 + d0] = kv;
                uint4 vv = *(const uint4*)(Vg + (size_t)kk * D_ + d0);
                unsigned short vs[8];
                *(uint4*)vs = vv;
#pragma unroll
                for (int j = 0; j < 8; ++j) {
                    int dd = d0 + j;
                    int boff = dd * 144 + ((kk * 2) ^ (((dd >> 3) & 7) << 4));
                    *(unsigned short*)((char*)VT_lds + boff) = vs[j];
                }
            }
        }
        __syncthreads();

        frag_ab kf[4][2];
#pragma unroll
        for (int kt = 0; kt < 4; ++kt) {
            const char* kp = (const char*)K_lds + (kt * 16 + l15) * 144 + g4 * 16;
            kf[kt][0] = *(const frag_ab*)kp;
            kf[kt][1] = *(const frag_ab*)(kp + 64);
        }
        frag_ab vf[4][2];
#pragma unroll
        for (int dt = 0; dt < 4; ++dt) {
            int drow = dt * 16 + l15;
            int swz = ((drow >> 3) & 7) << 4;
            const char* vp = (const char*)VT_lds + drow * 144;
            vf[dt][0] = *(const frag_ab*)(vp + ((g4 * 16) ^ swz));
            vf[dt][1] = *(const frag_ab*)(vp + ((g4 * 16 + 64) ^ swz));
        }

#pragma unroll
        for (int qt = 0; qt < 2; ++qt) {
            f32x4 st[4];
            __builtin_amdgcn_s_setprio(1);
#pragma unroll
            for (int kt = 0; kt < 4; ++kt) {
                f32x4 z = (f32x4){0.f, 0.f, 0.f, 0.f};
                z = __builtin_amdgcn_mfma_f32_16x16x32_bf16(kf[kt][0], qf[qt][0], z, 0, 0, 0);
                z = __builtin_amdgcn_mfma_f32_16x16x32_bf16(kf[kt][1], qf[qt][1], z, 0, 0, 0);
                st[kt] = z;
            }
            __builtin_amdgcn_s_setprio(0);
            int qa = cbase + w * 32 + qt * 16 + l15;
            float sv[16];
            float mx = -1e30f;
#pragma unroll
            for (int kt = 0; kt < 4; ++kt)
#pragma unroll
                for (int r = 0; r < 4; ++r) {
                    int ka = k0 + kt * 16 + g4 * 4 + r;
                    float s = st[kt][r] * 0.125f;
                    bool bad = (ka < NG_) | (ka - qa > W_) | (qa - ka > W_);
                    s = bad ? -1e30f : s;
                    sv[kt * 4 + r] = s;
                    mx = fmaxf(mx, s);
                }
            mx = fmaxf(mx, __shfl_xor(mx, 16));
            mx = fmaxf(mx, __shfl_xor(mx, 32));
            float mnew = fmaxf(fmaxf(mrun[qt], mx), -60.0f);
            if (__any(mnew != mrun[qt])) {
                float fsc = __expf(mrun[qt] - mnew);
                mrun[qt] = mnew;
#pragma unroll
                for (int dt = 0; dt < 4; ++dt) o[qt][dt] *= fsc;
                lrun[qt] *= fsc;
            }
            float psum = 0.f;
            unsigned short pb[16];
#pragma unroll
            for (int i = 0; i < 16; ++i) {
                float p = __expf(sv[i] - mrun[qt]);
                psum += p;
                pb[i] = f2bfu(p);
            }
            psum += __shfl_xor(psum, 16);
            psum += __shfl_xor(psum, 32);
            lrun[qt] += psum;
#pragma unroll
            for (int kt = 0; kt < 4; ++kt)
#pragma unroll
                for (int rp = 0; rp < 2; ++rp) {
                    unsigned vpk = (unsigned)pb[kt * 4 + rp * 2] | ((unsigned)pb[kt * 4 + rp * 2 + 1] << 16);
                    int kloc = kt * 16 + g4 * 4 + rp * 2;
                    *(unsigned*)(Pw + l15 * 144 + kloc * 2) = vpk;
                }
            frag_ab pf0 = *(const frag_ab*)(Pw + l15 * 144 + g4 * 16);
            frag_ab pf1 = *(const frag_ab*)(Pw + l15 * 144 + g4 * 16 + 64);
            __builtin_amdgcn_s_setprio(1);
#pragma unroll
            for (int dt = 0; dt < 4; ++dt) {
                o[qt][dt] = __builtin_amdgcn_mfma_f32_16x16x32_bf16(vf[dt][0], pf0, o[qt][dt], 0, 0, 0);
                o[qt][dt] = __builtin_amdgcn_mfma_f32_16x16x32_bf16(vf[dt][1], pf1, o[qt][dt], 0, 0, 0);
            }
            __builtin_amdgcn_s_setprio(0);
        }
    }

    // ---- 3 global keys (unmasked), scalar epilogue ----
    uint4 kgc[3][2];
    uint2 vgd[3][4];
#pragma unroll
    for (int gk = 0; gk < NG_; ++gk) {
        const __hip_bfloat16* kp = K + (size_t)(b * S_ + gk) * D_ + h * DH_ + g4 * 8;
        kgc[gk][0] = *(const uint4*)kp;
        kgc[gk][1] = *(const uint4*)(kp + 32);
        const __hip_bfloat16* vp = V + (size_t)(b * S_ + gk) * D_ + h * DH_ + g4 * 4;
#pragma unroll
        for (int dt = 0; dt < 4; ++dt)
            vgd[gk][dt] = *(const uint2*)(vp + dt * 16);
    }
#pragma unroll
    for (int qt = 0; qt < 2; ++qt) {
        float sg[3];
#pragma unroll
        for (int gk = 0; gk < NG_; ++gk) {
            float part = 0.f;
#pragma unroll
            for (int s = 0; s < 2; ++s) {
                uint4 qw = *(uint4*)&qf[qt][s];
                uint4 kw = kgc[gk][s];
                part += bflo(qw.x) * bflo(kw.x) + bfhi(qw.x) * bfhi(kw.x);
                part += bflo(qw.y) * bflo(kw.y) + bfhi(qw.y) * bfhi(kw.y);
                part += bflo(qw.z) * bflo(kw.z) + bfhi(qw.z) * bfhi(kw.z);
                part += bflo(qw.w) * bflo(kw.w) + bfhi(qw.w) * bfhi(kw.w);
            }
            part += __shfl_xor(part, 16);
            part += __shfl_xor(part, 32);
            sg[gk] = part * 0.125f;
        }
        float mx3 = fmaxf(fmaxf(sg[0], sg[1]), sg[2]);
        float mnew = fmaxf(fmaxf(mrun[qt], mx3), -60.0f);
        float fsc = __expf(mrun[qt] - mnew);
        mrun[qt] = mnew;
#pragma unroll
        for (int dt = 0; dt < 4; ++dt) o[qt][dt] *= fsc;
        lrun[qt] *= fsc;
        float pg[3];
        float psum = 0.f;
#pragma unroll
        for (int gk = 0; gk < NG_; ++gk) { pg[gk] = __expf(sg[gk] - mnew); psum += pg[gk]; }
        lrun[qt] += psum;
#pragma unroll
        for (int dt = 0; dt < 4; ++dt) {
#pragma unroll
            for (int gk = 0; gk < NG_; ++gk) {
                uint2 vv = vgd[gk][dt];
                o[qt][dt][0] += pg[gk] * bflo(vv.x);
                o[qt][dt][1] += pg[gk] * bfhi(vv.x);
                o[qt][dt][2] += pg[gk] * bflo(vv.y);
                o[qt][dt][3] += pg[gk] * bfhi(vv.y);
            }
        }
    }

#pragma unroll
    for (int qt = 0; qt < 2; ++qt) {
        float linv = 1.0f / lrun[qt];
        int qa = cbase + w * 32 + qt * 16 + l15;
        __hip_bfloat16* orow = O + (size_t)(b * S_ + qa) * D_ + h * DH_;
#pragma unroll
        for (int dt = 0; dt < 4; ++dt) {
            unsigned short pk[4];
#pragma unroll
            for (int r = 0; r < 4; ++r) pk[r] = f2bfu(o[qt][dt][r] * linv);
            *(uint2*)(orow + dt * 16 + g4 * 4) = *(uint2*)pk;
        }
    }
}

// ---------------- global attention, split-S flash decode ----------------
__global__ __launch_bounds__(256) void gattn_part_k(
    const float* __restrict__ qg, const __hip_bfloat16* __restrict__ KG,
    const __hip_bfloat16* __restrict__ VG, float* __restrict__ gpart) {
    __shared__ float sc[256];
    __shared__ float qs[DH_];
    __shared__ float red[256];
    __shared__ float rv[16][64];
    int split = blockIdx.x;
    int gh = blockIdx.y;
    int g = gh / H_, h = gh - g * H_;
    int b = blockIdx.z;
    int tid = threadIdx.x;
    if (tid < DH_) qs[tid] = qg[(size_t)(b * NG_ + g) * D_ + h * DH_ + tid] * 0.125f;
    __syncthreads();
    int s0 = split * (S_ / NSPLIT_);
    float acc = 0.f;
    {
        const __hip_bfloat16* kp = KG + (size_t)(b * S_ + s0 + tid) * D_ + h * DH_;
#pragma unroll
        for (int c8 = 0; c8 < 8; ++c8) {
            uint4 t = *(const uint4*)(kp + c8 * 8);
            float f[8]; unp8(t, f);
#pragma unroll
            for (int j = 0; j < 8; ++j) acc += qs[c8 * 8 + j] * f[j];
        }
    }
    float m = block_max(acc, red);
    float e = __expf(acc - m);
    sc[tid] = e;
    float l = block_sum(e, red);
    int sgq = tid >> 4, dq = (tid & 15) * 4;
    float a0 = 0.f, a1 = 0.f, a2 = 0.f, a3 = 0.f;
    const __hip_bfloat16* vbase = VG + (size_t)(b * S_ + s0 + sgq * 16) * D_ + h * DH_ + dq;
#pragma unroll
    for (int i = 0; i < 16; ++i) {
        float p = sc[sgq * 16 + i];
        uint2 vv = *(const uint2*)(vbase + (size_t)i * D_);
        a0 += p * bflo(vv.x); a1 += p * bfhi(vv.x);
        a2 += p * bflo(vv.y); a3 += p * bfhi(vv.y);
    }
    rv[sgq][dq] = a0; rv[sgq][dq + 1] = a1; rv[sgq][dq + 2] = a2; rv[sgq][dq + 3] = a3;
    __syncthreads();
    float* op = gpart + ((size_t)((b * NG_ + g) * H_ + h) * NSPLIT_ + split) * 66;
    if (tid == 0) { op[0] = m; op[1] = l; }
    if (tid < DH_) {
        float s = 0.f;
#pragma unroll
        for (int j = 0; j < 16; ++j) s += rv[j][tid];
        op[2 + tid] = s;
    }
}

template <typename TO>
__global__ __launch_bounds__(64) void gattn_comb_k(
    const float* __restrict__ gpart, TO* __restrict__ outp, int rowStride) {
    int g = blockIdx.x, h = blockIdx.y, b = blockIdx.z;
    int tid = threadIdx.x;
    const float* base = gpart + (size_t)((b * NG_ + g) * H_ + h) * NSPLIT_ * 66;
    float M = -1e30f;
#pragma unroll
    for (int p = 0; p < NSPLIT_; ++p) M = fmaxf(M, base[p * 66]);
    float l = 0.f, o = 0.f;
#pragma unroll
    for (int p = 0; p < NSPLIT_; ++p) {
        float wgt = __expf(base[p * 66] - M);
        l += wgt * base[p * 66 + 1];
        o += wgt * base[p * 66 + 2 + tid];
    }
    storeO(&outp[(size_t)(b * rowStride + g) * D_ + h * DH_ + tid], o / l);
}

// ---------------- gather the 6 global-token rows ----------------
__global__ void gather6_k(const float* __restrict__ X, float* __restrict__ xg) {
    int r = blockIdx.x;
    int b = r / NG_, g = r % NG_;
    for (int c = threadIdx.x; c < D_; c += blockDim.x)
        xg[(size_t)r * D_ + c] = X[(size_t)(b * S_ + g) * D_ + c];
}

// ---------------- classifier heads ----------------
__global__ __launch_bounds__(256) void classifier_k(
    const float* __restrict__ x26, const float* __restrict__ cw,
    const float* __restrict__ cb, float* __restrict__ out) {
    __shared__ float red[256];
    int tid = threadIdx.x;
    for (int i = 0; i < 3; ++i) {
        for (int b = 0; b < B_; ++b) {
            const float* xr = x26 + (size_t)(b * NG_ + i) * D_;
            const float* wr = cw + (size_t)i * D_;
            float p = 0.f;
            for (int c = tid; c < D_; c += 256) p += xr[c] * wr[c];
            float dotv = block_sum(p, red);
            if (tid == 0) out[i * B_ + b] = 1.0f / (1.0f + __expf(-(dotv + cb[i])));
        }
    }
    if (tid == 0) { out[6] = 1.0f; out[7] = 1.0f; }
}

// ---------------- host launcher ----------------
extern "C" void kernel_launch(void* const* d_in, const int* in_sizes, int n_in,
                              void* d_out, int out_size, void* d_ws, size_t ws_size,
                              hipStream_t stream) {
    const int*   src      = (const int*)d_in[0];
    const float* word_emb = (const float*)d_in[3];
    const float* pos_emb  = (const float*)d_in[4];
    const float* emb_ln   = (const float*)d_in[5];
    const float* attn_w   = (const float*)d_in[6];
    const float* attn_b   = (const float*)d_in[7];
    const float* ln_p     = (const float*)d_in[8];
    const float* ffn_w1   = (const float*)d_in[9];
    const float* ffn_b1   = (const float*)d_in[10];
    const float* ffn_w2   = (const float*)d_in[11];
    const float* ffn_b2   = (const float*)d_in[12];
    const float* cls_w    = (const float*)d_in[13];
    const float* cls_b    = (const float*)d_in[14];
    float* out = (float*)d_out;

    const size_t NT = (size_t)B_ * S_ * D_;  // 6291456 elements
    // -------- workspace layout (floats), NO overlaps --------
    float* base = (float*)d_ws;
    float* X  = base;
    float* P4 = base + NT;
    __hip_bfloat16* Xb  = (__hip_bfloat16*)(base + 2 * NT);
    __hip_bfloat16* Qb  = (__hip_bfloat16*)(base + 5 * NT / 2);
    __hip_bfloat16* Kb  = (__hip_bfloat16*)(base + 3 * NT);
    __hip_bfloat16* Vb  = (__hip_bfloat16*)(base + 7 * NT / 2);
    __hip_bfloat16* KGb = (__hip_bfloat16*)(base + 4 * NT);
    __hip_bfloat16* VGb = (__hip_bfloat16*)(base + 9 * NT / 2);
    __hip_bfloat16* AOb = (__hip_bfloat16*)(base + 5 * NT);
    __hip_bfloat16* HCb = (__hip_bfloat16*)(base + 11 * NT / 2);   // 2NT floats
    float* pj1 = base + 15 * NT / 2;
    float* pj2 = base + 17 * NT / 2;
    __hip_bfloat16* wq5 = (__hip_bfloat16*)(base + 19 * NT / 2);   // 5 x 768x768
    __hip_bfloat16* wo  = wq5 + 5 * 589824;
    __hip_bfloat16* wg1 = wo + 589824;                  // layer-1 kg/vg pair
    __hip_bfloat16* wf1 = wg1 + 2 * 589824;             // 3072x768
    __hip_bfloat16* wf2 = wf1 + 2359296;                // 768x3072
    float* SM  = (float*)(wf2 + 2359296);
    float* xg  = SM;
    float* qg6 = xg + 6 * D_;
    float* og6 = qg6 + 6 * D_;
    float* pr6 = og6 + 6 * D_;
    float* xa6 = pr6 + 6 * D_;
    float* h6  = xa6 + 6 * D_;
    float* f6  = h6 + 6 * FF_;
    float* x26 = f6 + 6 * D_;
    float* bias5 = x26 + 6 * D_;        // 3840
    float* part = bias5 + 5 * D_;       // split-K skinny partials
    float* gpart = part;                // aliased (never live simultaneously)

    const int M = B_ * S_;
    dim3 blk(256);

    auto aw = [&](int l, int i) { return attn_w + ((size_t)(l * 7 + i)) * D_ * D_; };
    auto ab = [&](int l, int i) { return attn_b + (size_t)(l * 7 + i) * D_; };
    auto lnp = [&](int l, int i) { return ln_p + (size_t)(l * 4 + i) * D_; };

    auto skinny = [&](const float* A6, const float* Wm, const float* bias,
                      float* out6, int N, int K, int gelu) {
        skinny_gemm_k<<<dim3(N / 64, K / 64), blk, 0, stream>>>(A6, Wm, part, N, K);
        skinny_reduce_k<<<dim3((6 * N + 255) / 256), blk, 0, stream>>>(part, bias, out6, N, K / 64, gelu);
    };

    embed_ln_k<<<M, blk, 0, stream>>>(src, word_emb, pos_emb, emb_ln, emb_ln + D_, X, Xb);

    // ================= layer 0 =================
    // mega projection: [Q,K,V,KG,VG] = Xb @ [wq wk wv wg1 wg2]^T  (N=3840)
    convt_k<<<dim3(24 * 3, 24), blk, 0, stream>>>(aw(0, 0), wq5, D_, D_, 24);
    convt_k<<<dim3(24 * 2, 24), blk, 0, stream>>>(aw(0, 4), wq5 + 3 * 589824, D_, D_, 24);
    pack_bias_k<<<15, blk, 0, stream>>>(ab(0, 0), bias5);
    mfma_gemm_k<1, 1><<<dim3(3840 / 128, 64), blk, 0, stream>>>(Xb, wq5, bias5, Qb, M, 3840, D_, NT);
    local_attn_k<<<dim3(S_ / QB_, H_, B_), blk, 0, stream>>>(Qb, Kb, Vb, AOb);
    gather6_k<<<B_ * NG_, blk, 0, stream>>>(X, xg);
    skinny(xg, aw(0, 3), ab(0, 3), qg6, D_, D_, 0);
    gattn_part_k<<<dim3(NSPLIT_, NG_ * H_, B_), blk, 0, stream>>>(qg6, KGb, VGb, gpart);
    gattn_comb_k<__hip_bfloat16><<<dim3(NG_, H_, B_), dim3(64), 0, stream>>>(gpart, AOb, S_);
    // attn output projection, split-K x2 -> pj1/pj2, combined in residual LN
    convt_k<<<dim3(24, 24), blk, 0, stream>>>(aw(0, 6), wo, D_, D_, 24);
    mfma_gemm_k<0, 0><<<dim3(6, 64, 2), blk, 0, stream>>>(AOb, wo, ab(0, 6), pj1, M, D_, D_, 0);
    residual_ln_k<<<M, blk, 0, stream>>>(X, pj1, pj2, lnp(0, 0), lnp(0, 1), P4, Xb);
    // FFN (full-M)
    convt_k<<<dim3(96, 24), blk, 0, stream>>>(ffn_w1, wf1, D_, FF_, 96);
    convt_k<<<dim3(24, 96), blk, 0, stream>>>(ffn_w2, wf2, FF_, D_, 24);
    mfma_gemm_k<2, 0><<<dim3(24, 64), blk, 0, stream>>>(Xb, wf1, ffn_b1, HCb, M, FF_, D_, 0);
    mfma_gemm_k<0, 0><<<dim3(6, 64, 2), blk, 0, stream>>>(HCb, wf2, ffn_b2, pj1, M, D_, FF_, 0);
    residual_ln_k<<<M, blk, 0, stream>>>(P4, pj1, pj2, lnp(0, 2), lnp(0, 3), X, Xb);

    // ================= layer 1 (pruned) =================
    convt_k<<<dim3(24 * 2, 24), blk, 0, stream>>>(aw(1, 4), wg1, D_, D_, 24);
    mfma_gemm_k<1, 1><<<dim3(1536 / 128, 64), blk, 0, stream>>>(Xb, wg1, ab(1, 4), KGb, M, 1536, D_, NT);
    gather6_k<<<B_ * NG_, blk, 0, stream>>>(X, xg);
    skinny(xg, aw(1, 3), ab(1, 3), qg6, D_, D_, 0);
    gattn_part_k<<<dim3(NSPLIT_, NG_ * H_, B_), blk, 0, stream>>>(qg6, KGb, VGb, gpart);
    gattn_comb_k<float><<<dim3(NG_, H_, B_), dim3(64), 0, stream>>>(gpart, og6, NG_);
    skinny(og6, aw(1, 6), ab(1, 6), pr6, D_, D_, 0);
    residual_ln_k<<<B_ * NG_, blk, 0, stream>>>(xg, pr6, nullptr, lnp(1, 0), lnp(1, 1), xa6, nullptr);
    skinny(xa6, ffn_w1 + (size_t)D_ * FF_, ffn_b1 + FF_, h6, FF_, D_, 1);
    skinny(h6, ffn_w2 + (size_t)FF_ * D_, ffn_b2 + D_, f6, D_, FF_, 0);
    residual_ln_k<<<B_ * NG_, blk, 0, stream>>>(xa6, f6, nullptr, lnp(1, 2), lnp(1, 3), x26, nullptr);
    classifier_k<<<1, blk, 0, stream>>>(x26, cls_w, cls_b, out);
}